// Round 8
// baseline (539.432 us; speedup 1.0000x reference)
//
#include <hip/hip_runtime.h>

typedef __bf16 bf16_t;
typedef __attribute__((ext_vector_type(8))) __bf16 bf16x8;
typedef __attribute__((ext_vector_type(4))) __bf16 bf16x4;
typedef __attribute__((ext_vector_type(4))) float f32x4;
typedef __attribute__((ext_vector_type(16))) float f32x16;

constexpr int Bc = 4, Sc = 2048, Dc = 512, Hc = 4, HDc = 128;
constexpr int Mrows = Bc * Sc;  // 8192

// gl2lds contract (r5/r6 lesson): source address MUST be per-lane (any per-lane
// permutation ok — it's a gather); LDS dest is wave-uniform base + lane*16.
__device__ inline void gl2lds(const void* g, void* l) {
  __builtin_amdgcn_global_load_lds(
      (__attribute__((address_space(1))) void*)g,
      (__attribute__((address_space(3))) void*)l, 16, 0, 0);
}

// ---------- fused prep: X->bf16 + bias-frag pack + 5 weight transposes ----------
// Qbg[b,s,16] = [2a'x, 2a'y, 2a'z, 1, 0...]          (B-operand bias chunk)
// Kbg tile[b][t][kh][lane][8]: lane<32: key=lane, dims0-7 = [x,y,z,-a'|p|^2,0..];
//   lanes 32-63 (dims 8-15) = 0.  a' = alpha*sqrt(128).
__global__ __launch_bounds__(256) void prep_k(
    const float* __restrict__ X, bf16_t* __restrict__ xb,
    const float* __restrict__ pos, const float* __restrict__ alphap,
    bf16_t* __restrict__ Qbg, bf16_t* __restrict__ Kbg,
    const float* __restrict__ We, bf16_t* __restrict__ wtE,
    const float* __restrict__ Ws, bf16_t* __restrict__ wtS,
    const float* __restrict__ Wq, const float* __restrict__ Wk,
    const float* __restrict__ Wv, bf16_t* __restrict__ wtQKV) {
  const int bid = blockIdx.x;
  if (bid < 2048) {  // X -> bf16
    const long i = ((long)bid * 256 + threadIdx.x) * 8;
    const float4 a = *(const float4*)(X + i);
    const float4 c = *(const float4*)(X + i + 4);
    bf16x8 o;
    o[0] = (bf16_t)a.x; o[1] = (bf16_t)a.y; o[2] = (bf16_t)a.z; o[3] = (bf16_t)a.w;
    o[4] = (bf16_t)c.x; o[5] = (bf16_t)c.y; o[6] = (bf16_t)c.z; o[7] = (bf16_t)c.w;
    *(bf16x8*)(xb + i) = o;
    return;
  }
  if (bid < 2080) {  // position bias fragments
    const float ap = alphap[0] * 11.313708498984761f;  // alpha*sqrt(128)
    const int i = (bid - 2048) * 256 + threadIdx.x;    // b*2048+s
    const int b = i >> 11, s = i & 2047;
    const float x = pos[(long)i * 3], y = pos[(long)i * 3 + 1], z = pos[(long)i * 3 + 2];
    const float m2 = -ap * (x * x + y * y + z * z);
    bf16x8 qlo = {}, klo = {}, zer = {};
    qlo[0] = (bf16_t)(2.f * ap * x); qlo[1] = (bf16_t)(2.f * ap * y);
    qlo[2] = (bf16_t)(2.f * ap * z); qlo[3] = (bf16_t)1.0f;
    klo[0] = (bf16_t)x; klo[1] = (bf16_t)y; klo[2] = (bf16_t)z; klo[3] = (bf16_t)m2;
    *(bf16x8*)(Qbg + (long)i * 16) = qlo;
    *(bf16x8*)(Qbg + (long)i * 16 + 8) = zer;
    const int t = s >> 6, kh = (s >> 5) & 1, key = s & 31;
    const long kb = ((long)(b * 32 + t) * 2 + kh) * 512 + key * 8;
    *(bf16x8*)(Kbg + kb) = klo;
    *(bf16x8*)(Kbg + kb + 256) = zer;
    return;
  }
  __shared__ float tile[32][33];
  const float* src; bf16_t* dst; int K, N, local;
  if (bid < 2592)      { src = We; dst = wtE; K = 512;  N = 1024; local = bid - 2080; }
  else if (bid < 3104) { src = Ws; dst = wtS; K = 1024; N = 512;  local = bid - 2592; }
  else if (bid < 3360) { src = Wq; dst = wtQKV;          K = 512; N = 512; local = bid - 3104; }
  else if (bid < 3616) { src = Wk; dst = wtQKV + 262144; K = 512; N = 512; local = bid - 3360; }
  else                 { src = Wv; dst = wtQKV + 524288; K = 512; N = 512; local = bid - 3616; }
  const int nb = N / 32;
  const int n0 = (local % nb) * 32, k0 = (local / nb) * 32;
  const int tx = threadIdx.x & 31, ty = threadIdx.x >> 5;
#pragma unroll
  for (int i = 0; i < 4; i++)
    tile[ty + i * 8][tx] = src[(long)(k0 + ty + i * 8) * N + n0 + tx];
  __syncthreads();
#pragma unroll
  for (int i = 0; i < 4; i++)
    dst[(long)(n0 + ty + i * 8) * K + k0 + tx] = (bf16_t)tile[tx][ty + i * 8];
}

// ---------- 128xTN MFMA GEMM, BK=64, dbuf + XOR-swizzled LDS + XCD row-swizzle ----
// OMODE: 0 = relu+bias -> bf16 ; 1 = bias -> bf16 ; 2 = qkv scatter bf16
template <int OMODE, int TN, int NB>
__global__ __launch_bounds__(256, (TN == 128) ? 2 : 3) void gemm128_k(
    const bf16_t* __restrict__ A, const bf16_t* __restrict__ Bt,
    const float* __restrict__ bias0, const float* __restrict__ bias1,
    const float* __restrict__ bias2, void* __restrict__ out0,
    void* __restrict__ out1, void* __restrict__ out2, int N, int K) {
  __shared__ bf16_t As[2][128 * 64];
  __shared__ bf16_t Bs[2][TN * 64];
  constexpr int MT = (TN == 128) ? 4 : 2;
  constexpr int BI = (TN == 128) ? 4 : 2;
  constexpr int MW = (TN == 128) ? 64 : 32;
  const int t = threadIdx.x;
  const int p = blockIdx.x;
  const int slot = p >> 3;
  const int by = (p & 7) + 8 * (slot / NB);
  const int bx = slot % NB;
  const int n0 = bx * TN, m0 = by * 128;
  const int lane = t & 63, wave = t >> 6;
  const int quad = lane >> 4, ln = lane & 15;
  const int wm = (TN == 128) ? (wave >> 1) : wave;
  const int wn = (TN == 128) ? (wave & 1) : 0;
  const int l8 = lane >> 3, g = lane & 7;
  const bf16_t* aseg = A + (long)(m0 + wave * 32 + l8) * K + (g ^ l8) * 8;
  const bf16_t* bseg = Bt + (long)(n0 + wave * (BI * 8) + l8) * K + (g ^ l8) * 8;
  auto stage = [&](int buf, int k0) {
#pragma unroll
    for (int i = 0; i < 4; i++)
      gl2lds(aseg + (long)i * 8 * K + k0, &As[buf][(wave * 32 + i * 8) * 64]);
#pragma unroll
    for (int i = 0; i < BI; i++)
      gl2lds(bseg + (long)i * 8 * K + k0, &Bs[buf][(wave * BI * 8 + i * 8) * 64]);
  };
  f32x4 acc[MT][4] = {};
  stage(0, 0);
  const int niter = K / 64;
  for (int it = 0; it < niter; it++) {
    const int cur = it & 1;
    __syncthreads();
    if (it + 1 < niter) stage(1 - cur, (it + 1) * 64);
#pragma unroll
    for (int kc = 0; kc < 2; kc++) {
      bf16x8 af[MT], bfr[4];
#pragma unroll
      for (int mt = 0; mt < MT; mt++)
        af[mt] = *(const bf16x8*)&As[cur][(wm * MW + mt * 16 + ln) * 64 +
                                          (((kc * 4 + quad) ^ (ln & 7)) * 8)];
#pragma unroll
      for (int nt = 0; nt < 4; nt++)
        bfr[nt] = *(const bf16x8*)&Bs[cur][(wn * 64 + nt * 16 + ln) * 64 +
                                           (((kc * 4 + quad) ^ (ln & 7)) * 8)];
#pragma unroll
      for (int mt = 0; mt < MT; mt++)
#pragma unroll
        for (int nt = 0; nt < 4; nt++)
          acc[mt][nt] = __builtin_amdgcn_mfma_f32_16x16x32_bf16(af[mt], bfr[nt],
                                                                acc[mt][nt], 0, 0, 0);
    }
  }
#pragma unroll
  for (int nt = 0; nt < 4; nt++) {
    const int gcol = n0 + wn * 64 + nt * 16 + ln;
    if constexpr (OMODE == 0 || OMODE == 1) {
      const float bv = bias0[gcol];
      bf16_t* o = (bf16_t*)out0;
#pragma unroll
      for (int mt = 0; mt < MT; mt++)
#pragma unroll
        for (int r = 0; r < 4; r++) {
          const int grow = m0 + wm * MW + mt * 16 + quad * 4 + r;
          float vv = acc[mt][nt][r] + bv;
          if constexpr (OMODE == 0) vv = vv > 0.f ? vv : 0.f;
          o[(long)grow * N + gcol] = (bf16_t)vv;
        }
    } else {
      const int which = gcol >> 9, n = gcol & 511;
      const int hh = n >> 7, hd = n & 127;
      const float bv = (which == 0 ? bias0 : which == 1 ? bias1 : bias2)[n];
      bf16_t* o = (bf16_t*)(which == 0 ? out0 : which == 1 ? out1 : out2);
#pragma unroll
      for (int mt = 0; mt < MT; mt++)
#pragma unroll
        for (int r = 0; r < 4; r++) {
          const int grow = m0 + wm * MW + mt * 16 + quad * 4 + r;
          const int b = grow >> 11, s = grow & 2047;
          const float vv = acc[mt][nt][r] + bv;
          long idx;
          if (which == 0) {  // q: [b,h,s,128] row-major
            idx = ((long)((b * Hc + hh) * Sc + s)) * HDc + hd;
          } else if (which == 1) {  // k frag-native: [b,h,t][kh][c][lane][8]
            const int tt = s >> 6, kh = (s >> 5) & 1, key = s & 31;
            const int c = hd >> 4, lk = key + 32 * ((hd >> 3) & 1), j = hd & 7;
            idx = ((((long)((b * Hc + hh) * 32 + tt) * 2 + kh) * 8 + c) * 64 + lk) * 8 + j;
          } else {  // v frag-native, key-slot bits2<->3 swapped: [b,h,t][ht][kc][lane][8]
            const int tt = s >> 6, ht2 = hd >> 5, kc2 = (s & 63) >> 4;
            const int kl = s & 15;
            const int klp = (kl & 3) | ((kl & 4) << 1) | ((kl & 8) >> 1);
            const int lk = (hd & 31) + 32 * (klp >> 3), j = klp & 7;
            idx = ((((long)((b * Hc + hh) * 32 + tt) * 4 + ht2) * 4 + kc2) * 64 + lk) * 8 + j;
          }
          o[idx] = (bf16_t)vv;
        }
    }
  }
}

// ---------- LayerNorm(xa + xb): one wave per row of 512, lane = 8 cols ----------
template <int AF32, int OF32>
__global__ __launch_bounds__(256) void ln_k(const void* __restrict__ xa,
                                            const bf16_t* __restrict__ xb,
                                            const float* __restrict__ gamma,
                                            const float* __restrict__ beta,
                                            void* __restrict__ out) {
  const int wave = threadIdx.x >> 6, lane = threadIdx.x & 63;
  const long row = (long)blockIdx.x * 4 + wave;
  const int col0 = lane * 8;
  float vv[8];
  float s = 0.f, s2 = 0.f;
  const bf16x8 vb = *(const bf16x8*)(xb + row * Dc + col0);
  if constexpr (AF32) {
    const float* a = (const float*)xa + row * Dc + col0;
    const float4 a0 = *(const float4*)a;
    const float4 a1 = *(const float4*)(a + 4);
    const float xs[8] = {a0.x, a0.y, a0.z, a0.w, a1.x, a1.y, a1.z, a1.w};
#pragma unroll
    for (int j = 0; j < 8; j++) vv[j] = xs[j] + (float)vb[j];
  } else {
    const bf16x8 va = *(const bf16x8*)((const bf16_t*)xa + row * Dc + col0);
#pragma unroll
    for (int j = 0; j < 8; j++) vv[j] = (float)va[j] + (float)vb[j];
  }
#pragma unroll
  for (int j = 0; j < 8; j++) { s += vv[j]; s2 += vv[j] * vv[j]; }
#pragma unroll
  for (int off = 1; off < 64; off <<= 1) {
    s += __shfl_xor(s, off, 64);
    s2 += __shfl_xor(s2, off, 64);
  }
  const float mu = s * (1.f / Dc);
  const float var = s2 * (1.f / Dc) - mu * mu;
  const float rstd = rsqrtf(var + 1e-5f);
  const float4 g0 = *(const float4*)(gamma + col0);
  const float4 g1 = *(const float4*)(gamma + col0 + 4);
  const float4 b0 = *(const float4*)(beta + col0);
  const float4 b1 = *(const float4*)(beta + col0 + 4);
  const float gs[8] = {g0.x, g0.y, g0.z, g0.w, g1.x, g1.y, g1.z, g1.w};
  const float bs[8] = {b0.x, b0.y, b0.z, b0.w, b1.x, b1.y, b1.z, b1.w};
  if constexpr (OF32) {
    float* o = (float*)out + row * Dc + col0;
    float4 o0, o1;
    o0.x = (vv[0] - mu) * rstd * gs[0] + bs[0];
    o0.y = (vv[1] - mu) * rstd * gs[1] + bs[1];
    o0.z = (vv[2] - mu) * rstd * gs[2] + bs[2];
    o0.w = (vv[3] - mu) * rstd * gs[3] + bs[3];
    o1.x = (vv[4] - mu) * rstd * gs[4] + bs[4];
    o1.y = (vv[5] - mu) * rstd * gs[5] + bs[5];
    o1.z = (vv[6] - mu) * rstd * gs[6] + bs[6];
    o1.w = (vv[7] - mu) * rstd * gs[7] + bs[7];
    *(float4*)o = o0; *(float4*)(o + 4) = o1;
  } else {
    bf16x8 ob;
#pragma unroll
    for (int j = 0; j < 8; j++) ob[j] = (bf16_t)((vv[j] - mu) * rstd * gs[j] + bs[j]);
    *(bf16x8*)((bf16_t*)out + row * Dc + col0) = ob;
  }
}

// ---------- flash attention: S^T = K Q^T + MFMA-folded bias ----------
// 8-wave split-K blocks: wave = (rh, kh, ks); ks halves the K-tile range so the
// grid packs 16 waves/CU (4/SIMD) instead of 8 — latency hiding doubles.
// Main loop is barrier-free and all-register (K/V/Kb prefetch-after-use);
// P never leaves registers (V layout carries key bit2<->3 swap).
__global__ __launch_bounds__(512, 4) void attn_k(const bf16_t* __restrict__ q,
                                                 const bf16_t* __restrict__ Kg,
                                                 const bf16_t* __restrict__ Vg,
                                                 const bf16_t* __restrict__ Qbg,
                                                 const bf16_t* __restrict__ Kbg,
                                                 bf16_t* __restrict__ ctx) {
  __shared__ float Oc[16384];  // ks-combine (64KB), then kh-combine reuse
  __shared__ float RsD[8][32];
  const int t = threadIdx.x;
  const int p = blockIdx.x;
  const int qt = (p >> 3) & 31;
  const int gg = (p & 7) + 8 * (p >> 8);
  const int h = gg & 3, b = gg >> 2;
  const int q0 = qt * 64;
  const int wave = t >> 6, lane = t & 63;
  const int l31 = lane & 31, hb = lane >> 5;
  const int rh = wave & 1, kh = (wave >> 1) & 1, ks = wave >> 2;
  const float scale_l2 = 1.4426950408889634f * 0.08838834764831845f;  // log2e/sqrt(128)

  // Q fragments (B-operand): q-col = q0+rh*32+l31 (lane-fixed); bias chunk from Qbg
  bf16x8 qf[8], qbf;
  const long qrow = (long)((b * Hc + h) * Sc + q0 + rh * 32 + l31);
#pragma unroll
  for (int c = 0; c < 8; c++)
    qf[c] = *(const bf16x8*)(q + qrow * HDc + c * 16 + hb * 8);
  qbf = *(const bf16x8*)(Qbg + (long)(b * Sc + q0 + rh * 32 + l31) * 16 + hb * 8);

  // per-lane frag bases; ks selects K-tile half [ks*16, ks*16+16)
  const bf16_t* kfb = Kg + (long)((b * Hc + h) * 32 + ks * 16) * 8192 +
                      (kh * 8) * 512 + lane * 8;
  const bf16_t* vfb = Vg + (long)((b * Hc + h) * 32 + ks * 16) * 8192 +
                      kh * 1024 + lane * 8;
  const bf16_t* kbb = Kbg + (long)(b * 32 + ks * 16) * 1024 + kh * 512 + lane * 8;

  bf16x8 kr[8], vr[8], kbr;
#pragma unroll
  for (int c = 0; c < 8; c++) kr[c] = *(const bf16x8*)(kfb + c * 512);
  kbr = *(const bf16x8*)(kbb);
#pragma unroll
  for (int i = 0; i < 8; i++)
    vr[i] = *(const bf16x8*)(vfb + (i >> 1) * 2048 + (i & 1) * 512);

  float rsl = 0.f;
  f32x16 accT[4] = {};

  for (int kt = 0; kt < 16; kt++) {
    // ---- QK^T on registers: two independent accumulator chains ----
    f32x16 sa = {}, sb = {};
    __builtin_amdgcn_s_setprio(1);
#pragma unroll
    for (int c = 0; c < 4; c++)
      sa = __builtin_amdgcn_mfma_f32_32x32x16_bf16(kr[c], qf[c], sa, 0, 0, 0);
#pragma unroll
    for (int c = 4; c < 8; c++)
      sb = __builtin_amdgcn_mfma_f32_32x32x16_bf16(kr[c], qf[c], sb, 0, 0, 0);
    sb = __builtin_amdgcn_mfma_f32_32x32x16_bf16(kbr, qbf, sb, 0, 0, 0);
    __builtin_amdgcn_s_setprio(0);
    __builtin_amdgcn_sched_barrier(0);  // keep K prefetch BELOW its consumers
    // ---- prefetch K(kt+1) (hides under softmax+PV); final iter reads one
    //      tile past — lands in the adjacent allocated workspace region.
    {
      const long noff = (long)(kt + 1) * 8192;
#pragma unroll
      for (int c = 0; c < 8; c++)
        kr[c] = *(const bf16x8*)(kfb + noff + c * 512);
      kbr = *(const bf16x8*)(kbb + (long)(kt + 1) * 1024);
    }
    // ---- softmax numerator; native pe[] order IS the PV B-frag order ----
    const f32x16 sacc = sa + sb;
    float pe[16];
#pragma unroll
    for (int i = 0; i < 16; i++) {
      pe[i] = __builtin_amdgcn_exp2f(sacc[i] * scale_l2);
      rsl += pe[i];
    }
    bf16x8 pf0, pf1;
#pragma unroll
    for (int j = 0; j < 8; j++) { pf0[j] = (bf16_t)pe[j]; pf1[j] = (bf16_t)pe[8 + j]; }
    // ---- O^T += V^T P^T on registers ----
    __builtin_amdgcn_s_setprio(1);
#pragma unroll
    for (int ht = 0; ht < 4; ht++) {
      accT[ht] = __builtin_amdgcn_mfma_f32_32x32x16_bf16(vr[2 * ht], pf0, accT[ht], 0, 0, 0);
      accT[ht] = __builtin_amdgcn_mfma_f32_32x32x16_bf16(vr[2 * ht + 1], pf1, accT[ht], 0, 0, 0);
    }
    __builtin_amdgcn_s_setprio(0);
    __builtin_amdgcn_sched_barrier(0);  // keep V prefetch BELOW PV
    // ---- prefetch V(kt+1); hides under next QK^T+softmax ----
    {
      const long noff = (long)(kt + 1) * 8192;
#pragma unroll
      for (int i = 0; i < 8; i++)
        vr[i] = *(const bf16x8*)(vfb + noff + (i >> 1) * 2048 + (i & 1) * 512);
    }
  }

  // ---------------- epilogue: ks-combine, then kh-combine ----------------
  rsl += __shfl_xor(rsl, 32, 64);
  if (hb == 0) RsD[wave][l31] = rsl;
  if (ks == 1) {  // export ks=1 partials
    float* dst = &Oc[(wave - 4) * 4096];
#pragma unroll
    for (int ht = 0; ht < 4; ht++)
#pragma unroll
      for (int r = 0; r < 16; r++)
        dst[(ht * 16 + r) * 64 + lane] = accT[ht][r];
  }
  __syncthreads();
  if (ks == 0) {  // fold partner's partial
    const float* src = &Oc[wave * 4096];
#pragma unroll
    for (int ht = 0; ht < 4; ht++)
#pragma unroll
      for (int r = 0; r < 16; r++)
        accT[ht][r] += src[(ht * 16 + r) * 64 + lane];
  }
  __syncthreads();
  if (ks == 0 && kh == 1) {
#pragma unroll
    for (int ht = 0; ht < 4; ht++)
#pragma unroll
      for (int r = 0; r < 16; r++) {
        const int hdp = (r & 3) + 8 * (r >> 2) + 4 * hb;
        Oc[(ht * 32 + hdp) * 64 + rh * 32 + l31] = accT[ht][r];
      }
  }
  __syncthreads();
  if (ks == 0 && kh == 0) {
    const float rinv = 1.f / (RsD[rh][l31] + RsD[rh + 2][l31] +
                              RsD[rh + 4][l31] + RsD[rh + 6][l31]);
    const long orow = (long)(b * Sc + q0 + rh * 32 + l31);
#pragma unroll
    for (int ht = 0; ht < 4; ht++)
#pragma unroll
      for (int g2 = 0; g2 < 4; g2++) {
        bf16x4 ov;
#pragma unroll
        for (int r0 = 0; r0 < 4; r0++) {
          const int hdp = r0 + 8 * g2 + 4 * hb;
          ov[r0] = (bf16_t)((accT[ht][g2 * 4 + r0] +
                             Oc[(ht * 32 + hdp) * 64 + rh * 32 + l31]) * rinv);
        }
        *(bf16x4*)(ctx + orow * Dc + h * HDc + ht * 32 + 8 * g2 + 4 * hb) = ov;
      }
  }
}

// ---------------- workspace layout (bytes) ----------------
constexpr size_t SQB_OFF = 0;                      // bf16 8192x512: squeeze out, later ctx
constexpr size_t SEB_OFF = 8388608;                // bf16 8192x512: se
constexpr size_t Q_OFF = 16777216;                 // bf16 8192x512 (Xb aliases)
constexpr size_t K_OFF = 25165824;                 // bf16 tiled 8 MB
constexpr size_t V_OFF = 33554432;                 // bf16 tiled 8 MB
constexpr size_t XB_OFF = Q_OFF;                   // dead before q written
constexpr size_t H_OFF = K_OFF;                    // dead before k/v written
constexpr size_t QBG_OFF = 41943040;               // bf16 8192x16 = 256 KB
constexpr size_t KBG_OFF = QBG_OFF + 262144;       // bf16 128 tiles x 1024 = 256 KB
constexpr size_t WTE_OFF = KBG_OFF + 262144;       // bf16 1024x512 (1 MB)
constexpr size_t WTS_OFF = WTE_OFF + 1048576;      // bf16 512x1024 (1 MB)
constexpr size_t WTQKV_OFF = WTS_OFF + 1048576;    // bf16 1536x512 (1.5 MB)
// end = 46,137,344 bytes

extern "C" void kernel_launch(void* const* d_in, const int* in_sizes, int n_in,
                              void* d_out, int out_size, void* d_ws, size_t ws_size,
                              hipStream_t stream) {
  const float* X = (const float*)d_in[0];
  const float* pos = (const float*)d_in[1];
  const float* W_expand = (const float*)d_in[2];
  const float* b_expand = (const float*)d_in[3];
  const float* W_squeeze = (const float*)d_in[4];
  const float* b_squeeze = (const float*)d_in[5];
  const float* gamma = (const float*)d_in[6];
  const float* beta = (const float*)d_in[7];
  const float* Wq = (const float*)d_in[8];
  const float* bq = (const float*)d_in[9];
  const float* Wk = (const float*)d_in[10];
  const float* bk = (const float*)d_in[11];
  const float* Wv = (const float*)d_in[12];
  const float* bv = (const float*)d_in[13];
  const float* alphap = (const float*)d_in[14];

  char* ws = (char*)d_ws;
  bf16_t* sqb = (bf16_t*)(ws + SQB_OFF);
  bf16_t* ctxb = (bf16_t*)(ws + SQB_OFF);  // reuses sqb (sq dead after LN1)
  bf16_t* seb = (bf16_t*)(ws + SEB_OFF);
  bf16_t* qbg = (bf16_t*)(ws + QBG_OFF);
  bf16_t* kbg = (bf16_t*)(ws + KBG_OFF);
  bf16_t* qb = (bf16_t*)(ws + Q_OFF);
  bf16_t* kb = (bf16_t*)(ws + K_OFF);
  bf16_t* vb = (bf16_t*)(ws + V_OFF);
  bf16_t* xbb = (bf16_t*)(ws + XB_OFF);
  bf16_t* hb = (bf16_t*)(ws + H_OFF);
  bf16_t* wtE = (bf16_t*)(ws + WTE_OFF);
  bf16_t* wtS = (bf16_t*)(ws + WTS_OFF);
  bf16_t* wtQKV = (bf16_t*)(ws + WTQKV_OFF);

  // prep: X cast + bias frags + weight transposes (one launch)
  prep_k<<<3872, 256, 0, stream>>>(X, xbb, pos, alphap, qbg, kbg,
                                   W_expand, wtE, W_squeeze, wtS, Wq, Wk, Wv, wtQKV);
  // h = relu(X @ We + be)            [8192,1024] bf16
  gemm128_k<0, 128, 8><<<512, 256, 0, stream>>>(
      xbb, wtE, b_expand, nullptr, nullptr, hb, nullptr, nullptr, 1024, 512);
  // sq = h @ Ws + bs                 [8192,512] bf16
  gemm128_k<1, 64, 8><<<512, 256, 0, stream>>>(
      hb, wtS, b_squeeze, nullptr, nullptr, sqb, nullptr, nullptr, 512, 1024);
  // se = LN(X + sq)  -> bf16
  ln_k<1, 0><<<Mrows / 4, 256, 0, stream>>>(X, sqb, gamma, beta, seb);
  // q,k,v = se @ [Wq|Wk|Wv] + b
  gemm128_k<2, 128, 12><<<768, 256, 0, stream>>>(
      seb, wtQKV, bq, bk, bv, qb, kb, vb, 1536, 512);
  // ctx = attention (bias folded into MFMA), 8-wave split-K blocks
  attn_k<<<512, 512, 0, stream>>>(qb, kb, vb, qbg, kbg, ctxb);
  // out = LN(se + ctx) -> fp32
  ln_k<0, 1><<<Mrows / 4, 256, 0, stream>>>(seb, ctxb, gamma, beta, (float*)d_out);

  (void)in_sizes; (void)n_in; (void)out_size; (void)ws_size;
}

// Round 9
// 212.663 us; speedup vs baseline: 2.5366x; 2.5366x over previous
//
#include <hip/hip_runtime.h>

typedef __bf16 bf16_t;
typedef __attribute__((ext_vector_type(8))) __bf16 bf16x8;
typedef __attribute__((ext_vector_type(4))) __bf16 bf16x4;
typedef __attribute__((ext_vector_type(4))) float f32x4;
typedef __attribute__((ext_vector_type(16))) float f32x16;

constexpr int Bc = 4, Sc = 2048, Dc = 512, Hc = 4, HDc = 128;
constexpr int Mrows = Bc * Sc;  // 8192

// gl2lds contract (r5/r6 lesson): source address MUST be per-lane (any per-lane
// permutation ok — it's a gather); LDS dest is wave-uniform base + lane*16.
__device__ inline void gl2lds(const void* g, void* l) {
  __builtin_amdgcn_global_load_lds(
      (__attribute__((address_space(1))) void*)g,
      (__attribute__((address_space(3))) void*)l, 16, 0, 0);
}

// ---------- fused prep: X->bf16 + bias-frag pack + 5 weight transposes ----------
// Qbg[b,s,16] = [2a'x, 2a'y, 2a'z, 1, 0...]          (B-operand bias chunk)
// Kbg tile[b][t][kh][lane][8]: lane<32: key=lane, dims0-7 = [x,y,z,-a'|p|^2,0..];
//   lanes 32-63 (dims 8-15) = 0.  a' = alpha*sqrt(128).
__global__ __launch_bounds__(256) void prep_k(
    const float* __restrict__ X, bf16_t* __restrict__ xb,
    const float* __restrict__ pos, const float* __restrict__ alphap,
    bf16_t* __restrict__ Qbg, bf16_t* __restrict__ Kbg,
    const float* __restrict__ We, bf16_t* __restrict__ wtE,
    const float* __restrict__ Ws, bf16_t* __restrict__ wtS,
    const float* __restrict__ Wq, const float* __restrict__ Wk,
    const float* __restrict__ Wv, bf16_t* __restrict__ wtQKV) {
  const int bid = blockIdx.x;
  if (bid < 2048) {  // X -> bf16
    const long i = ((long)bid * 256 + threadIdx.x) * 8;
    const float4 a = *(const float4*)(X + i);
    const float4 c = *(const float4*)(X + i + 4);
    bf16x8 o;
    o[0] = (bf16_t)a.x; o[1] = (bf16_t)a.y; o[2] = (bf16_t)a.z; o[3] = (bf16_t)a.w;
    o[4] = (bf16_t)c.x; o[5] = (bf16_t)c.y; o[6] = (bf16_t)c.z; o[7] = (bf16_t)c.w;
    *(bf16x8*)(xb + i) = o;
    return;
  }
  if (bid < 2080) {  // position bias fragments
    const float ap = alphap[0] * 11.313708498984761f;  // alpha*sqrt(128)
    const int i = (bid - 2048) * 256 + threadIdx.x;    // b*2048+s
    const int b = i >> 11, s = i & 2047;
    const float x = pos[(long)i * 3], y = pos[(long)i * 3 + 1], z = pos[(long)i * 3 + 2];
    const float m2 = -ap * (x * x + y * y + z * z);
    bf16x8 qlo = {}, klo = {}, zer = {};
    qlo[0] = (bf16_t)(2.f * ap * x); qlo[1] = (bf16_t)(2.f * ap * y);
    qlo[2] = (bf16_t)(2.f * ap * z); qlo[3] = (bf16_t)1.0f;
    klo[0] = (bf16_t)x; klo[1] = (bf16_t)y; klo[2] = (bf16_t)z; klo[3] = (bf16_t)m2;
    *(bf16x8*)(Qbg + (long)i * 16) = qlo;
    *(bf16x8*)(Qbg + (long)i * 16 + 8) = zer;
    const int t = s >> 6, kh = (s >> 5) & 1, key = s & 31;
    const long kb = ((long)(b * 32 + t) * 2 + kh) * 512 + key * 8;
    *(bf16x8*)(Kbg + kb) = klo;
    *(bf16x8*)(Kbg + kb + 256) = zer;
    return;
  }
  __shared__ float tile[32][33];
  const float* src; bf16_t* dst; int K, N, local;
  if (bid < 2592)      { src = We; dst = wtE; K = 512;  N = 1024; local = bid - 2080; }
  else if (bid < 3104) { src = Ws; dst = wtS; K = 1024; N = 512;  local = bid - 2592; }
  else if (bid < 3360) { src = Wq; dst = wtQKV;          K = 512; N = 512; local = bid - 3104; }
  else if (bid < 3616) { src = Wk; dst = wtQKV + 262144; K = 512; N = 512; local = bid - 3360; }
  else                 { src = Wv; dst = wtQKV + 524288; K = 512; N = 512; local = bid - 3616; }
  const int nb = N / 32;
  const int n0 = (local % nb) * 32, k0 = (local / nb) * 32;
  const int tx = threadIdx.x & 31, ty = threadIdx.x >> 5;
#pragma unroll
  for (int i = 0; i < 4; i++)
    tile[ty + i * 8][tx] = src[(long)(k0 + ty + i * 8) * N + n0 + tx];
  __syncthreads();
#pragma unroll
  for (int i = 0; i < 4; i++)
    dst[(long)(n0 + ty + i * 8) * K + k0 + tx] = (bf16_t)tile[tx][ty + i * 8];
}

// ---------- 128xTN MFMA GEMM, BK=64, dbuf + XOR-swizzled LDS + XCD row-swizzle ----
// OMODE: 0 = relu+bias -> bf16 ; 1 = bias -> bf16 ; 2 = qkv scatter bf16
template <int OMODE, int TN, int NB>
__global__ __launch_bounds__(256, (TN == 128) ? 2 : 3) void gemm128_k(
    const bf16_t* __restrict__ A, const bf16_t* __restrict__ Bt,
    const float* __restrict__ bias0, const float* __restrict__ bias1,
    const float* __restrict__ bias2, void* __restrict__ out0,
    void* __restrict__ out1, void* __restrict__ out2, int N, int K) {
  __shared__ bf16_t As[2][128 * 64];
  __shared__ bf16_t Bs[2][TN * 64];
  constexpr int MT = (TN == 128) ? 4 : 2;
  constexpr int BI = (TN == 128) ? 4 : 2;
  constexpr int MW = (TN == 128) ? 64 : 32;
  const int t = threadIdx.x;
  const int p = blockIdx.x;
  const int slot = p >> 3;
  const int by = (p & 7) + 8 * (slot / NB);
  const int bx = slot % NB;
  const int n0 = bx * TN, m0 = by * 128;
  const int lane = t & 63, wave = t >> 6;
  const int quad = lane >> 4, ln = lane & 15;
  const int wm = (TN == 128) ? (wave >> 1) : wave;
  const int wn = (TN == 128) ? (wave & 1) : 0;
  const int l8 = lane >> 3, g = lane & 7;
  const bf16_t* aseg = A + (long)(m0 + wave * 32 + l8) * K + (g ^ l8) * 8;
  const bf16_t* bseg = Bt + (long)(n0 + wave * (BI * 8) + l8) * K + (g ^ l8) * 8;
  auto stage = [&](int buf, int k0) {
#pragma unroll
    for (int i = 0; i < 4; i++)
      gl2lds(aseg + (long)i * 8 * K + k0, &As[buf][(wave * 32 + i * 8) * 64]);
#pragma unroll
    for (int i = 0; i < BI; i++)
      gl2lds(bseg + (long)i * 8 * K + k0, &Bs[buf][(wave * BI * 8 + i * 8) * 64]);
  };
  f32x4 acc[MT][4] = {};
  stage(0, 0);
  const int niter = K / 64;
  for (int it = 0; it < niter; it++) {
    const int cur = it & 1;
    __syncthreads();
    if (it + 1 < niter) stage(1 - cur, (it + 1) * 64);
#pragma unroll
    for (int kc = 0; kc < 2; kc++) {
      bf16x8 af[MT], bfr[4];
#pragma unroll
      for (int mt = 0; mt < MT; mt++)
        af[mt] = *(const bf16x8*)&As[cur][(wm * MW + mt * 16 + ln) * 64 +
                                          (((kc * 4 + quad) ^ (ln & 7)) * 8)];
#pragma unroll
      for (int nt = 0; nt < 4; nt++)
        bfr[nt] = *(const bf16x8*)&Bs[cur][(wn * 64 + nt * 16 + ln) * 64 +
                                           (((kc * 4 + quad) ^ (ln & 7)) * 8)];
#pragma unroll
      for (int mt = 0; mt < MT; mt++)
#pragma unroll
        for (int nt = 0; nt < 4; nt++)
          acc[mt][nt] = __builtin_amdgcn_mfma_f32_16x16x32_bf16(af[mt], bfr[nt],
                                                                acc[mt][nt], 0, 0, 0);
    }
  }
#pragma unroll
  for (int nt = 0; nt < 4; nt++) {
    const int gcol = n0 + wn * 64 + nt * 16 + ln;
    if constexpr (OMODE == 0 || OMODE == 1) {
      const float bv = bias0[gcol];
      bf16_t* o = (bf16_t*)out0;
#pragma unroll
      for (int mt = 0; mt < MT; mt++)
#pragma unroll
        for (int r = 0; r < 4; r++) {
          const int grow = m0 + wm * MW + mt * 16 + quad * 4 + r;
          float vv = acc[mt][nt][r] + bv;
          if constexpr (OMODE == 0) vv = vv > 0.f ? vv : 0.f;
          o[(long)grow * N + gcol] = (bf16_t)vv;
        }
    } else {
      const int which = gcol >> 9, n = gcol & 511;
      const int hh = n >> 7, hd = n & 127;
      const float bv = (which == 0 ? bias0 : which == 1 ? bias1 : bias2)[n];
      bf16_t* o = (bf16_t*)(which == 0 ? out0 : which == 1 ? out1 : out2);
#pragma unroll
      for (int mt = 0; mt < MT; mt++)
#pragma unroll
        for (int r = 0; r < 4; r++) {
          const int grow = m0 + wm * MW + mt * 16 + quad * 4 + r;
          const int b = grow >> 11, s = grow & 2047;
          const float vv = acc[mt][nt][r] + bv;
          long idx;
          if (which == 0) {  // q: [b,h,s,128] row-major
            idx = ((long)((b * Hc + hh) * Sc + s)) * HDc + hd;
          } else if (which == 1) {  // k frag-native: [b,h,t][kh][c][lane][8]
            const int tt = s >> 6, kh = (s >> 5) & 1, key = s & 31;
            const int c = hd >> 4, lk = key + 32 * ((hd >> 3) & 1), j = hd & 7;
            idx = ((((long)((b * Hc + hh) * 32 + tt) * 2 + kh) * 8 + c) * 64 + lk) * 8 + j;
          } else {  // v frag-native, key-slot bits2<->3 swapped: [b,h,t][ht][kc][lane][8]
            const int tt = s >> 6, ht2 = hd >> 5, kc2 = (s & 63) >> 4;
            const int kl = s & 15;
            const int klp = (kl & 3) | ((kl & 4) << 1) | ((kl & 8) >> 1);
            const int lk = (hd & 31) + 32 * (klp >> 3), j = klp & 7;
            idx = ((((long)((b * Hc + hh) * 32 + tt) * 4 + ht2) * 4 + kc2) * 64 + lk) * 8 + j;
          }
          o[idx] = (bf16_t)vv;
        }
    }
  }
}

// ---------- LayerNorm(xa + xb): one wave per row of 512, lane = 8 cols ----------
template <int AF32, int OF32>
__global__ __launch_bounds__(256) void ln_k(const void* __restrict__ xa,
                                            const bf16_t* __restrict__ xb,
                                            const float* __restrict__ gamma,
                                            const float* __restrict__ beta,
                                            void* __restrict__ out) {
  const int wave = threadIdx.x >> 6, lane = threadIdx.x & 63;
  const long row = (long)blockIdx.x * 4 + wave;
  const int col0 = lane * 8;
  float vv[8];
  float s = 0.f, s2 = 0.f;
  const bf16x8 vb = *(const bf16x8*)(xb + row * Dc + col0);
  if constexpr (AF32) {
    const float* a = (const float*)xa + row * Dc + col0;
    const float4 a0 = *(const float4*)a;
    const float4 a1 = *(const float4*)(a + 4);
    const float xs[8] = {a0.x, a0.y, a0.z, a0.w, a1.x, a1.y, a1.z, a1.w};
#pragma unroll
    for (int j = 0; j < 8; j++) vv[j] = xs[j] + (float)vb[j];
  } else {
    const bf16x8 va = *(const bf16x8*)((const bf16_t*)xa + row * Dc + col0);
#pragma unroll
    for (int j = 0; j < 8; j++) vv[j] = (float)va[j] + (float)vb[j];
  }
#pragma unroll
  for (int j = 0; j < 8; j++) { s += vv[j]; s2 += vv[j] * vv[j]; }
#pragma unroll
  for (int off = 1; off < 64; off <<= 1) {
    s += __shfl_xor(s, off, 64);
    s2 += __shfl_xor(s2, off, 64);
  }
  const float mu = s * (1.f / Dc);
  const float var = s2 * (1.f / Dc) - mu * mu;
  const float rstd = rsqrtf(var + 1e-5f);
  const float4 g0 = *(const float4*)(gamma + col0);
  const float4 g1 = *(const float4*)(gamma + col0 + 4);
  const float4 b0 = *(const float4*)(beta + col0);
  const float4 b1 = *(const float4*)(beta + col0 + 4);
  const float gs[8] = {g0.x, g0.y, g0.z, g0.w, g1.x, g1.y, g1.z, g1.w};
  const float bs[8] = {b0.x, b0.y, b0.z, b0.w, b1.x, b1.y, b1.z, b1.w};
  if constexpr (OF32) {
    float* o = (float*)out + row * Dc + col0;
    float4 o0, o1;
    o0.x = (vv[0] - mu) * rstd * gs[0] + bs[0];
    o0.y = (vv[1] - mu) * rstd * gs[1] + bs[1];
    o0.z = (vv[2] - mu) * rstd * gs[2] + bs[2];
    o0.w = (vv[3] - mu) * rstd * gs[3] + bs[3];
    o1.x = (vv[4] - mu) * rstd * gs[4] + bs[4];
    o1.y = (vv[5] - mu) * rstd * gs[5] + bs[5];
    o1.z = (vv[6] - mu) * rstd * gs[6] + bs[6];
    o1.w = (vv[7] - mu) * rstd * gs[7] + bs[7];
    *(float4*)o = o0; *(float4*)(o + 4) = o1;
  } else {
    bf16x8 ob;
#pragma unroll
    for (int j = 0; j < 8; j++) ob[j] = (bf16_t)((vv[j] - mu) * rstd * gs[j] + bs[j]);
    *(bf16x8*)((bf16_t*)out + row * Dc + col0) = ob;
  }
}

// ---------- flash attention: S^T = K Q^T + MFMA-folded bias ----------
// Barrier-free all-register loop. Prefetch blocks are PINNED between
// sched_barrier(0) pairs: without the trailing barrier the pressure-aware
// scheduler sinks the loads to their uses (R7 emitted only 112 VGPRs — the
// prefetch never existed; ~300cy L2 latency exposed every cluster). Pinning
// forces issue a full phase ahead; ~210 VGPR, still 2 waves/SIMD, no spill.
__global__ __launch_bounds__(256, 2) void attn_k(const bf16_t* __restrict__ q,
                                                 const bf16_t* __restrict__ Kg,
                                                 const bf16_t* __restrict__ Vg,
                                                 const bf16_t* __restrict__ Qbg,
                                                 const bf16_t* __restrict__ Kbg,
                                                 bf16_t* __restrict__ ctx) {
  __shared__ float Oc[8192];  // epilogue cross-wave O^T exchange (32 KB)
  __shared__ float RsD[4][32];
  const int t = threadIdx.x;
  const int p = blockIdx.x;
  const int qt = (p >> 3) & 31;
  const int gg = (p & 7) + 8 * (p >> 8);
  const int h = gg & 3, b = gg >> 2;
  const int q0 = qt * 64;
  const int wave = t >> 6, lane = t & 63;
  const int l31 = lane & 31, hb = lane >> 5;
  const int rh = wave & 1, kh = wave >> 1;
  const float scale_l2 = 1.4426950408889634f * 0.08838834764831845f;  // log2e/sqrt(128)

  // Q fragments (B-operand): q-col = q0+rh*32+l31 (lane-fixed); bias chunk from Qbg
  bf16x8 qf[8], qbf;
  const long qrow = (long)((b * Hc + h) * Sc + q0 + rh * 32 + l31);
#pragma unroll
  for (int c = 0; c < 8; c++)
    qf[c] = *(const bf16x8*)(q + qrow * HDc + c * 16 + hb * 8);
  qbf = *(const bf16x8*)(Qbg + (long)(b * Sc + q0 + rh * 32 + l31) * 16 + hb * 8);

  // per-lane frag bases (each wave loads exactly the frags it consumes)
  const bf16_t* kfb = Kg + (long)((b * Hc + h) * 32) * 8192 + (kh * 8) * 512 + lane * 8;
  const bf16_t* vfb = Vg + (long)((b * Hc + h) * 32) * 8192 + kh * 1024 + lane * 8;
  const bf16_t* kbb = Kbg + (long)(b * 32) * 1024 + kh * 512 + lane * 8;

  bf16x8 kr[8], vr[8], kbr;
#pragma unroll
  for (int c = 0; c < 8; c++) kr[c] = *(const bf16x8*)(kfb + c * 512);
  kbr = *(const bf16x8*)(kbb);
#pragma unroll
  for (int i = 0; i < 8; i++)
    vr[i] = *(const bf16x8*)(vfb + (i >> 1) * 2048 + (i & 1) * 512);

  float rsl = 0.f;
  f32x16 accT[4] = {};

  for (int kt = 0; kt < 32; kt++) {
    // ---- QK^T on registers (tile kt): two independent accumulator chains ----
    f32x16 sa = {}, sb = {};
    __builtin_amdgcn_s_setprio(1);
#pragma unroll
    for (int c = 0; c < 4; c++)
      sa = __builtin_amdgcn_mfma_f32_32x32x16_bf16(kr[c], qf[c], sa, 0, 0, 0);
#pragma unroll
    for (int c = 4; c < 8; c++)
      sb = __builtin_amdgcn_mfma_f32_32x32x16_bf16(kr[c], qf[c], sb, 0, 0, 0);
    sb = __builtin_amdgcn_mfma_f32_32x32x16_bf16(kbr, qbf, sb, 0, 0, 0);
    __builtin_amdgcn_s_setprio(0);
    __builtin_amdgcn_sched_barrier(0);
    // ---- prefetch K(kt+1), PINNED here (issue a full phase before use).
    //      Final iter reads one tile past — lands in adjacent allocated ws.
    {
      const long noff = (long)(kt + 1) * 8192;
#pragma unroll
      for (int c = 0; c < 8; c++)
        kr[c] = *(const bf16x8*)(kfb + noff + c * 512);
      kbr = *(const bf16x8*)(kbb + (long)(kt + 1) * 1024);
    }
    __builtin_amdgcn_sched_barrier(0);  // forbid sinking the K loads downward
    // ---- softmax numerator; native pe[] order IS the PV B-frag order ----
    const f32x16 sacc = sa + sb;
    float pe[16];
#pragma unroll
    for (int i = 0; i < 16; i++) {
      pe[i] = __builtin_amdgcn_exp2f(sacc[i] * scale_l2);
      rsl += pe[i];
    }
    bf16x8 pf0, pf1;
#pragma unroll
    for (int j = 0; j < 8; j++) { pf0[j] = (bf16_t)pe[j]; pf1[j] = (bf16_t)pe[8 + j]; }
    // ---- O^T += V^T P^T on registers ----
    __builtin_amdgcn_s_setprio(1);
#pragma unroll
    for (int ht = 0; ht < 4; ht++) {
      accT[ht] = __builtin_amdgcn_mfma_f32_32x32x16_bf16(vr[2 * ht], pf0, accT[ht], 0, 0, 0);
      accT[ht] = __builtin_amdgcn_mfma_f32_32x32x16_bf16(vr[2 * ht + 1], pf1, accT[ht], 0, 0, 0);
    }
    __builtin_amdgcn_s_setprio(0);
    __builtin_amdgcn_sched_barrier(0);
    // ---- prefetch V(kt+1), PINNED (hides under next QK^T+softmax) ----
    {
      const long noff = (long)(kt + 1) * 8192;
#pragma unroll
      for (int i = 0; i < 8; i++)
        vr[i] = *(const bf16x8*)(vfb + noff + (i >> 1) * 2048 + (i & 1) * 512);
    }
    __builtin_amdgcn_sched_barrier(0);  // forbid sinking the V loads downward
  }
  __syncthreads();

  rsl += __shfl_xor(rsl, 32, 64);
  if (hb == 0) RsD[wave][l31] = rsl;
  if (kh == 1) {
#pragma unroll
    for (int ht = 0; ht < 4; ht++)
#pragma unroll
      for (int r = 0; r < 16; r++) {
        const int hdp = (r & 3) + 8 * (r >> 2) + 4 * hb;
        Oc[(ht * 32 + hdp) * 64 + rh * 32 + l31] = accT[ht][r];
      }
  }
  __syncthreads();
  if (kh == 0) {
    const float rinv = 1.f / (RsD[wave][l31] + RsD[wave + 2][l31]);
    const long orow = (long)(b * Sc + q0 + rh * 32 + l31);
#pragma unroll
    for (int ht = 0; ht < 4; ht++)
#pragma unroll
      for (int g2 = 0; g2 < 4; g2++) {
        bf16x4 ov;
#pragma unroll
        for (int r0 = 0; r0 < 4; r0++) {
          const int hdp = r0 + 8 * g2 + 4 * hb;
          ov[r0] = (bf16_t)((accT[ht][g2 * 4 + r0] +
                             Oc[(ht * 32 + hdp) * 64 + rh * 32 + l31]) * rinv);
        }
        *(bf16x4*)(ctx + orow * Dc + h * HDc + ht * 32 + 8 * g2 + 4 * hb) = ov;
      }
  }
}

// ---------------- workspace layout (bytes) ----------------
constexpr size_t SQB_OFF = 0;                      // bf16 8192x512: squeeze out, later ctx
constexpr size_t SEB_OFF = 8388608;                // bf16 8192x512: se
constexpr size_t Q_OFF = 16777216;                 // bf16 8192x512 (Xb aliases)
constexpr size_t K_OFF = 25165824;                 // bf16 tiled 8 MB
constexpr size_t V_OFF = 33554432;                 // bf16 tiled 8 MB
constexpr size_t XB_OFF = Q_OFF;                   // dead before q written
constexpr size_t H_OFF = K_OFF;                    // dead before k/v written
constexpr size_t QBG_OFF = 41943040;               // bf16 8192x16 = 256 KB
constexpr size_t KBG_OFF = QBG_OFF + 262144;       // bf16 128 tiles x 1024 = 256 KB
constexpr size_t WTE_OFF = KBG_OFF + 262144;       // bf16 1024x512 (1 MB)
constexpr size_t WTS_OFF = WTE_OFF + 1048576;      // bf16 512x1024 (1 MB)
constexpr size_t WTQKV_OFF = WTS_OFF + 1048576;    // bf16 1536x512 (1.5 MB)
// end = 46,137,344 bytes

extern "C" void kernel_launch(void* const* d_in, const int* in_sizes, int n_in,
                              void* d_out, int out_size, void* d_ws, size_t ws_size,
                              hipStream_t stream) {
  const float* X = (const float*)d_in[0];
  const float* pos = (const float*)d_in[1];
  const float* W_expand = (const float*)d_in[2];
  const float* b_expand = (const float*)d_in[3];
  const float* W_squeeze = (const float*)d_in[4];
  const float* b_squeeze = (const float*)d_in[5];
  const float* gamma = (const float*)d_in[6];
  const float* beta = (const float*)d_in[7];
  const float* Wq = (const float*)d_in[8];
  const float* bq = (const float*)d_in[9];
  const float* Wk = (const float*)d_in[10];
  const float* bk = (const float*)d_in[11];
  const float* Wv = (const float*)d_in[12];
  const float* bv = (const float*)d_in[13];
  const float* alphap = (const float*)d_in[14];

  char* ws = (char*)d_ws;
  bf16_t* sqb = (bf16_t*)(ws + SQB_OFF);
  bf16_t* ctxb = (bf16_t*)(ws + SQB_OFF);  // reuses sqb (sq dead after LN1)
  bf16_t* seb = (bf16_t*)(ws + SEB_OFF);
  bf16_t* qbg = (bf16_t*)(ws + QBG_OFF);
  bf16_t* kbg = (bf16_t*)(ws + KBG_OFF);
  bf16_t* qb = (bf16_t*)(ws + Q_OFF);
  bf16_t* kb = (bf16_t*)(ws + K_OFF);
  bf16_t* vb = (bf16_t*)(ws + V_OFF);
  bf16_t* xbb = (bf16_t*)(ws + XB_OFF);
  bf16_t* hb = (bf16_t*)(ws + H_OFF);
  bf16_t* wtE = (bf16_t*)(ws + WTE_OFF);
  bf16_t* wtS = (bf16_t*)(ws + WTS_OFF);
  bf16_t* wtQKV = (bf16_t*)(ws + WTQKV_OFF);

  // prep: X cast + bias frags + weight transposes (one launch)
  prep_k<<<3872, 256, 0, stream>>>(X, xbb, pos, alphap, qbg, kbg,
                                   W_expand, wtE, W_squeeze, wtS, Wq, Wk, Wv, wtQKV);
  // h = relu(X @ We + be)            [8192,1024] bf16
  gemm128_k<0, 128, 8><<<512, 256, 0, stream>>>(
      xbb, wtE, b_expand, nullptr, nullptr, hb, nullptr, nullptr, 1024, 512);
  // sq = h @ Ws + bs                 [8192,512] bf16
  gemm128_k<1, 64, 8><<<512, 256, 0, stream>>>(
      hb, wtS, b_squeeze, nullptr, nullptr, sqb, nullptr, nullptr, 512, 1024);
  // se = LN(X + sq)  -> bf16
  ln_k<1, 0><<<Mrows / 4, 256, 0, stream>>>(X, sqb, gamma, beta, seb);
  // q,k,v = se @ [Wq|Wk|Wv] + b
  gemm128_k<2, 128, 12><<<768, 256, 0, stream>>>(
      seb, wtQKV, bq, bk, bv, qb, kb, vb, 1536, 512);
  // ctx = attention (bias folded into MFMA)
  attn_k<<<512, 256, 0, stream>>>(qb, kb, vb, qbg, kbg, ctxb);
  // out = LN(se + ctx) -> fp32
  ln_k<0, 1><<<Mrows / 4, 256, 0, stream>>>(seb, ctxb, gamma, beta, (float*)d_out);

  (void)in_sizes; (void)n_in; (void)out_size; (void)ws_size;
}